// Round 1
// baseline (346.505 us; speedup 1.0000x reference)
//
#include <hip/hip_runtime.h>

// GCN: h1 = relu(agg(x@W1)); h2 = relu(agg(h1@W2)); out = h2@Wfc + bfc
// agg_i = dinv_i * (y_i + sum_{j in N(i)} y_j) + b, where y = (x@W)*dinv[:,None],
// dinv_i = rsqrt(indeg_i + 1). CSR built per launch (fixed capacity 64/node).

#define CAP 64   // max in-degree capacity (Poisson mean 16 over 50k nodes, max ~35)

__global__ __launch_bounds__(256) void k_zero(int* __restrict__ p, int n) {
    int i = blockIdx.x * 256 + threadIdx.x;
    if (i < n) p[i] = 0;
}

__global__ __launch_bounds__(256) void k_fill(const int* __restrict__ src,
                                              const int* __restrict__ dst,
                                              int* __restrict__ cursor,
                                              int* __restrict__ csr, int E) {
    int e = blockIdx.x * 256 + threadIdx.x;
    if (e >= E) return;
    int d = dst[e];
    int p = atomicAdd(&cursor[d], 1);
    if (p < CAP) csr[(size_t)d * CAP + p] = src[e];
}

// Y[row][c] = dinv[row] * sum_k X[row][k] * W[k][c];  N fixed = 64 cols.
// 128 threads: tx=tid&7 (cols 8*tx..+7), ty=tid>>3 (rows ty+16*r, r=0..7).
template <int K>
__global__ __launch_bounds__(128) void k_gemm(const float* __restrict__ X,
                                              const float* __restrict__ W,
                                              const int* __restrict__ cnt,
                                              float* __restrict__ Y, int n) {
    constexpr int KC = 64;
    constexpr int XS = KC + 4;  // stride 68: 16B-aligned, rows 16 apart hit distinct banks
    __shared__ float ws[KC * 64];    // 16 KB
    __shared__ float xs[128 * XS];   // 34816 B
    const int tid = threadIdx.x;
    const int tx = tid & 7;
    const int ty = tid >> 3;
    const int row0 = blockIdx.x * 128;

    float acc[8][8];
#pragma unroll
    for (int r = 0; r < 8; r++)
#pragma unroll
        for (int c = 0; c < 8; c++) acc[r][c] = 0.f;

    for (int kc = 0; kc < K; kc += KC) {
        // stage W chunk: KC x 64
        for (int i = tid; i < KC * 16; i += 128) {
            int kk = i >> 4, c4 = i & 15;
            *(float4*)&ws[kk * 64 + 4 * c4] = *(const float4*)&W[(kc + kk) * 64 + 4 * c4];
        }
        // stage X chunk: 128 rows x KC
        for (int i = tid; i < 128 * (KC / 4); i += 128) {
            int r = i / (KC / 4), q = i % (KC / 4);
            float4 v = make_float4(0.f, 0.f, 0.f, 0.f);
            int row = row0 + r;
            if (row < n) v = *(const float4*)&X[(size_t)row * K + kc + 4 * q];
            *(float4*)&xs[r * XS + 4 * q] = v;
        }
        __syncthreads();

        for (int q = 0; q < KC / 4; q++) {
            float4 xv[8];
#pragma unroll
            for (int r = 0; r < 8; r++)
                xv[r] = *(const float4*)&xs[(ty + 16 * r) * XS + 4 * q];
#pragma unroll
            for (int kk = 0; kk < 4; kk++) {
                float4 wa = *(const float4*)&ws[(4 * q + kk) * 64 + 8 * tx];
                float4 wb = *(const float4*)&ws[(4 * q + kk) * 64 + 8 * tx + 4];
#pragma unroll
                for (int r = 0; r < 8; r++) {
                    float xval = (kk == 0) ? xv[r].x : (kk == 1) ? xv[r].y
                               : (kk == 2) ? xv[r].z : xv[r].w;
                    acc[r][0] = fmaf(xval, wa.x, acc[r][0]);
                    acc[r][1] = fmaf(xval, wa.y, acc[r][1]);
                    acc[r][2] = fmaf(xval, wa.z, acc[r][2]);
                    acc[r][3] = fmaf(xval, wa.w, acc[r][3]);
                    acc[r][4] = fmaf(xval, wb.x, acc[r][4]);
                    acc[r][5] = fmaf(xval, wb.y, acc[r][5]);
                    acc[r][6] = fmaf(xval, wb.z, acc[r][6]);
                    acc[r][7] = fmaf(xval, wb.w, acc[r][7]);
                }
            }
        }
        __syncthreads();
    }

#pragma unroll
    for (int r = 0; r < 8; r++) {
        int row = row0 + ty + 16 * r;
        if (row < n) {
            float d = rsqrtf((float)cnt[row] + 1.0f);
            float4 o0, o1;
            o0.x = acc[r][0] * d; o0.y = acc[r][1] * d;
            o0.z = acc[r][2] * d; o0.w = acc[r][3] * d;
            o1.x = acc[r][4] * d; o1.y = acc[r][5] * d;
            o1.z = acc[r][6] * d; o1.w = acc[r][7] * d;
            *(float4*)&Y[(size_t)row * 64 + 8 * tx]     = o0;
            *(float4*)&Y[(size_t)row * 64 + 8 * tx + 4] = o1;
        }
    }
}

// out[i][c] = relu( dinv_i * (y[i][c] + sum_j y[j][c]) + bias[c] )
// one wave per node, lane = feature channel.
__global__ __launch_bounds__(256) void k_agg(const float* __restrict__ y,
                                             const int* __restrict__ csr,
                                             const int* __restrict__ cnt,
                                             const float* __restrict__ bias,
                                             float* __restrict__ out, int n) {
    int node = (blockIdx.x * 256 + threadIdx.x) >> 6;
    int lane = threadIdx.x & 63;
    if (node >= n) return;
    int deg_raw = cnt[node];
    int deg = deg_raw > CAP ? CAP : deg_raw;
    float acc = y[(size_t)node * 64 + lane];  // self term
    const int* lst = csr + (size_t)node * CAP;
    for (int i = 0; i < deg; i++) {
        int j = lst[i];  // wave-uniform address -> broadcast
        acc += y[(size_t)j * 64 + lane];
    }
    float d = rsqrtf((float)deg_raw + 1.0f);
    float v = fmaf(d, acc, bias[lane]);
    out[(size_t)node * 64 + lane] = fmaxf(v, 0.f);
}

// out[i][c] = sum_k h[i][k] * Wfc[k][c] + bfc[c],  c < 12
__global__ __launch_bounds__(256) void k_fc(const float* __restrict__ h,
                                            const float* __restrict__ Wfc,
                                            const float* __restrict__ bfc,
                                            float* __restrict__ out, int n) {
    __shared__ float hs[64 * 64];
    __shared__ float wf[64 * 12];
    __shared__ float bf[12];
    int tid = threadIdx.x;
    int node0 = blockIdx.x * 64;
    for (int i = tid; i < 64 * 12; i += 256) wf[i] = Wfc[i];
    if (tid < 12) bf[tid] = bfc[tid];
    for (int f = tid; f < 1024; f += 256) {
        int r = f >> 4, c4 = f & 15;
        float4 v = make_float4(0.f, 0.f, 0.f, 0.f);
        if (node0 + r < n) v = *(const float4*)&h[(size_t)(node0 + r) * 64 + 4 * c4];
        *(float4*)&hs[r * 64 + 4 * c4] = v;
    }
    __syncthreads();
    for (int o = tid; o < 64 * 12; o += 256) {
        int r = o / 12, c = o % 12;
        if (node0 + r >= n) continue;
        float acc = bf[c];
        for (int k = 0; k < 64; k++) acc = fmaf(hs[r * 64 + k], wf[k * 12 + c], acc);
        out[(size_t)(node0 + r) * 12 + c] = acc;
    }
}

extern "C" void kernel_launch(void* const* d_in, const int* in_sizes, int n_in,
                              void* d_out, int out_size, void* d_ws, size_t ws_size,
                              hipStream_t stream) {
    const float* x   = (const float*)d_in[0];
    const int*   ei  = (const int*)d_in[1];
    const float* W1  = (const float*)d_in[2];
    const float* b1  = (const float*)d_in[3];
    const float* W2  = (const float*)d_in[4];
    const float* b2  = (const float*)d_in[5];
    const float* Wfc = (const float*)d_in[6];
    const float* bfc = (const float*)d_in[7];
    float* out = (float*)d_out;

    const int n = in_sizes[0] / 128;   // 50000
    const int E = in_sizes[1] / 2;     // 800000
    const int* src = ei;
    const int* dst = ei + E;

    // workspace layout (all 256B-aligned)
    char* w = (char*)d_ws;
    int* cursor = (int*)w;    w += (size_t)((n + 63) / 64) * 64 * 4;  // 200192 B
    int* csr    = (int*)w;    w += (size_t)n * CAP * 4;               // 12.8 MB
    float* y    = (float*)w;  w += (size_t)n * 64 * 4;                // 12.8 MB
    float* h    = (float*)w;                                          // 12.8 MB

    k_zero<<<dim3((n + 255) / 256), dim3(256), 0, stream>>>(cursor, n);
    k_fill<<<dim3((E + 255) / 256), dim3(256), 0, stream>>>(src, dst, cursor, csr, E);
    k_gemm<128><<<dim3((n + 127) / 128), dim3(128), 0, stream>>>(x, W1, cursor, y, n);
    k_agg<<<dim3((n + 3) / 4), dim3(256), 0, stream>>>(y, csr, cursor, b1, h, n);
    k_gemm<64><<<dim3((n + 127) / 128), dim3(128), 0, stream>>>(h, W2, cursor, y, n);
    k_agg<<<dim3((n + 3) / 4), dim3(256), 0, stream>>>(y, csr, cursor, b2, h, n);
    k_fc<<<dim3((n + 63) / 64), dim3(256), 0, stream>>>(h, Wfc, bfc, out, n);
}

// Round 2
// 260.589 us; speedup vs baseline: 1.3297x; 1.3297x over previous
//
#include <hip/hip_runtime.h>

// GCN: h1 = relu(agg(x@W1)); h2 = relu(agg(h1@W2)); out = h2@Wfc + bfc
// agg_i = dinv_i * (y_i + sum_{j in N(i)} y_j) + b, where y = (x@W)*dinv[:,None],
// dinv_i = rsqrt(indeg_i + 1). CSR built per launch (fixed capacity 64/node).

#define CAP 64   // max in-degree capacity (Poisson mean 16 over 50k nodes, max ~35)

__global__ __launch_bounds__(256) void k_zero(int* __restrict__ p, int n) {
    int i = blockIdx.x * 256 + threadIdx.x;
    if (i < n) p[i] = 0;
}

__global__ __launch_bounds__(256) void k_fill(const int* __restrict__ src,
                                              const int* __restrict__ dst,
                                              int* __restrict__ cursor,
                                              int* __restrict__ csr, int E) {
    int e = blockIdx.x * 256 + threadIdx.x;
    if (e >= E) return;
    int d = dst[e];
    int p = atomicAdd(&cursor[d], 1);
    if (p < CAP) csr[(size_t)d * CAP + p] = src[e];
}

// Y[row][c] = dinv[row] * sum_k X[row][k] * W[k][c];  64 output cols.
// 64-row x 64-col tile, 256 threads (4 waves), 4x4 register tile per thread.
// tx=tid&15 -> cols 4*tx..+3 ; ty=tid>>4 -> rows ty+16*r, r=0..3.
template <int K>
__global__ __launch_bounds__(256) void k_gemm(const float* __restrict__ X,
                                              const float* __restrict__ W,
                                              const int* __restrict__ cnt,
                                              float* __restrict__ Y, int n) {
    constexpr int KC = 64;
    constexpr int XS = KC + 4;        // stride 68: rows 1 apart -> banks 4 apart
    __shared__ float ws[KC * 64];     // 16 KB
    __shared__ float xs[64 * XS];     // 17408 B  (total ~33.4 KB -> ~4 blocks/CU LDS-wise)
    const int tid = threadIdx.x;
    const int tx = tid & 15;
    const int ty = tid >> 4;
    const int row0 = blockIdx.x * 64;

    float acc[4][4];
#pragma unroll
    for (int r = 0; r < 4; r++)
#pragma unroll
        for (int c = 0; c < 4; c++) acc[r][c] = 0.f;

    for (int kc = 0; kc < K; kc += KC) {
        // stage W chunk: KC x 64 (1024 float4s / 256 threads = 4 each)
        for (int i = tid; i < KC * 16; i += 256) {
            int kk = i >> 4, c4 = i & 15;
            *(float4*)&ws[kk * 64 + 4 * c4] = *(const float4*)&W[(kc + kk) * 64 + 4 * c4];
        }
        // stage X chunk: 64 rows x KC (1024 float4s)
        for (int i = tid; i < 64 * (KC / 4); i += 256) {
            int r = i / (KC / 4), q = i % (KC / 4);
            float4 v = make_float4(0.f, 0.f, 0.f, 0.f);
            int row = row0 + r;
            if (row < n) v = *(const float4*)&X[(size_t)row * K + kc + 4 * q];
            *(float4*)&xs[r * XS + 4 * q] = v;
        }
        __syncthreads();

        for (int q = 0; q < KC / 4; q++) {
            float4 xv[4];
#pragma unroll
            for (int r = 0; r < 4; r++)
                xv[r] = *(const float4*)&xs[(ty + 16 * r) * XS + 4 * q];
#pragma unroll
            for (int kk = 0; kk < 4; kk++) {
                float4 wv = *(const float4*)&ws[(4 * q + kk) * 64 + 4 * tx];
#pragma unroll
                for (int r = 0; r < 4; r++) {
                    float xval = (kk == 0) ? xv[r].x : (kk == 1) ? xv[r].y
                               : (kk == 2) ? xv[r].z : xv[r].w;
                    acc[r][0] = fmaf(xval, wv.x, acc[r][0]);
                    acc[r][1] = fmaf(xval, wv.y, acc[r][1]);
                    acc[r][2] = fmaf(xval, wv.z, acc[r][2]);
                    acc[r][3] = fmaf(xval, wv.w, acc[r][3]);
                }
            }
        }
        __syncthreads();
    }

#pragma unroll
    for (int r = 0; r < 4; r++) {
        int row = row0 + ty + 16 * r;
        if (row < n) {
            float d = rsqrtf((float)cnt[row] + 1.0f);
            float4 o;
            o.x = acc[r][0] * d; o.y = acc[r][1] * d;
            o.z = acc[r][2] * d; o.w = acc[r][3] * d;
            *(float4*)&Y[(size_t)row * 64 + 4 * tx] = o;
        }
    }
}

// out[i][c] = relu( dinv_i * (y[i][c] + sum_j y[j][c]) + bias[c] )
// one wave per node, lane = feature channel. Neighbor gathers unrolled x8
// with int4 index batching -> ~8 outstanding loads per wave (MLP, not latency chain).
__global__ __launch_bounds__(256) void k_agg(const float* __restrict__ y,
                                             const int* __restrict__ csr,
                                             const int* __restrict__ cnt,
                                             const float* __restrict__ bias,
                                             float* __restrict__ out, int n) {
    int node = (blockIdx.x * 256 + threadIdx.x) >> 6;
    int lane = threadIdx.x & 63;
    if (node >= n) return;
    int deg_raw = cnt[node];
    int deg = deg_raw > CAP ? CAP : deg_raw;
    const int* lst = csr + node * CAP;
    float acc = y[node * 64 + lane];  // self term
    int i = 0;
    for (; i + 8 <= deg; i += 8) {
        int4 a = *(const int4*)(lst + i);
        int4 b = *(const int4*)(lst + i + 4);
        float v0 = y[a.x * 64 + lane];
        float v1 = y[a.y * 64 + lane];
        float v2 = y[a.z * 64 + lane];
        float v3 = y[a.w * 64 + lane];
        float v4 = y[b.x * 64 + lane];
        float v5 = y[b.y * 64 + lane];
        float v6 = y[b.z * 64 + lane];
        float v7 = y[b.w * 64 + lane];
        acc += ((v0 + v1) + (v2 + v3)) + ((v4 + v5) + (v6 + v7));
    }
    if (i + 4 <= deg) {
        int4 a = *(const int4*)(lst + i);
        float v0 = y[a.x * 64 + lane];
        float v1 = y[a.y * 64 + lane];
        float v2 = y[a.z * 64 + lane];
        float v3 = y[a.w * 64 + lane];
        acc += (v0 + v1) + (v2 + v3);
        i += 4;
    }
    for (; i < deg; i++) acc += y[lst[i] * 64 + lane];
    float d = rsqrtf((float)deg_raw + 1.0f);
    float v = fmaf(d, acc, bias[lane]);
    out[node * 64 + lane] = fmaxf(v, 0.f);
}

// out[i][c] = sum_k h[i][k] * Wfc[k][c] + bfc[c],  c < 12
__global__ __launch_bounds__(256) void k_fc(const float* __restrict__ h,
                                            const float* __restrict__ Wfc,
                                            const float* __restrict__ bfc,
                                            float* __restrict__ out, int n) {
    __shared__ float hs[64 * 64];
    __shared__ float wf[64 * 12];
    __shared__ float bf[12];
    int tid = threadIdx.x;
    int node0 = blockIdx.x * 64;
    for (int i = tid; i < 64 * 12; i += 256) wf[i] = Wfc[i];
    if (tid < 12) bf[tid] = bfc[tid];
    for (int f = tid; f < 1024; f += 256) {
        int r = f >> 4, c4 = f & 15;
        float4 v = make_float4(0.f, 0.f, 0.f, 0.f);
        if (node0 + r < n) v = *(const float4*)&h[(size_t)(node0 + r) * 64 + 4 * c4];
        *(float4*)&hs[r * 64 + 4 * c4] = v;
    }
    __syncthreads();
    for (int o = tid; o < 64 * 12; o += 256) {
        int r = o / 12, c = o % 12;
        if (node0 + r >= n) continue;
        float acc = bf[c];
        for (int k = 0; k < 64; k++) acc = fmaf(hs[r * 64 + k], wf[k * 12 + c], acc);
        out[(size_t)(node0 + r) * 12 + c] = acc;
    }
}

extern "C" void kernel_launch(void* const* d_in, const int* in_sizes, int n_in,
                              void* d_out, int out_size, void* d_ws, size_t ws_size,
                              hipStream_t stream) {
    const float* x   = (const float*)d_in[0];
    const int*   ei  = (const int*)d_in[1];
    const float* W1  = (const float*)d_in[2];
    const float* b1  = (const float*)d_in[3];
    const float* W2  = (const float*)d_in[4];
    const float* b2  = (const float*)d_in[5];
    const float* Wfc = (const float*)d_in[6];
    const float* bfc = (const float*)d_in[7];
    float* out = (float*)d_out;

    const int n = in_sizes[0] / 128;   // 50000
    const int E = in_sizes[1] / 2;     // 800000
    const int* src = ei;
    const int* dst = ei + E;

    // workspace layout (all 256B-aligned)
    char* w = (char*)d_ws;
    int* cursor = (int*)w;    w += (size_t)((n + 63) / 64) * 64 * 4;  // 200192 B
    int* csr    = (int*)w;    w += (size_t)n * CAP * 4;               // 12.8 MB
    float* y    = (float*)w;  w += (size_t)n * 64 * 4;                // 12.8 MB
    float* h    = (float*)w;                                          // 12.8 MB

    k_zero<<<dim3((n + 255) / 256), dim3(256), 0, stream>>>(cursor, n);
    k_fill<<<dim3((E + 255) / 256), dim3(256), 0, stream>>>(src, dst, cursor, csr, E);
    k_gemm<128><<<dim3((n + 63) / 64), dim3(256), 0, stream>>>(x, W1, cursor, y, n);
    k_agg<<<dim3((n + 3) / 4), dim3(256), 0, stream>>>(y, csr, cursor, b1, h, n);
    k_gemm<64><<<dim3((n + 63) / 64), dim3(256), 0, stream>>>(h, W2, cursor, y, n);
    k_agg<<<dim3((n + 3) / 4), dim3(256), 0, stream>>>(y, csr, cursor, b2, h, n);
    k_fc<<<dim3((n + 63) / 64), dim3(256), 0, stream>>>(h, Wfc, bfc, out, n);
}